// Round 7
// baseline (336.385 us; speedup 1.0000x reference)
//
#include <hip/hip_runtime.h>

// VQ-VAE quantize: input (16,64,64,64) f32, embeddings (64,2048) f32.
// Outputs concat in d_out: quantize_st[4194304], loss[1], embed_ind[65536] (as float).
//
// Correctness-critical (absmax 0.0 in rounds 1,2,4,5,6 — do not change arithmetic):
//   dist = fl( fl(sx - 2*dot) + se ),  dot = sequential-k FMA chain (k=0..63),
//   sx = numpy pairwise (8 accumulators + tree), se = sequential axis-0 sum,
//   argmin = first index of minimum (strict <, ascending j; wave slices ascending).
//
// Structure: 8 waves/block, wave w owns codes [w*256, w*256+256). Codes staged
// in 8-code chunks through WAVE-PRIVATE LDS (no barriers in main loop); all
// lanes read the same LDS address -> HW broadcast, conflict-free.
//
// Round-7: rounds 4-6 showed VGPR_Count pinned at 64 with ~2.6x VALU issue and
// no scratch traffic -> allocator split the unified file 64 VGPR + ~64 AGPR
// (occupancy 43% = 4 waves/SIMD residency) and pays v_accvgpr_read per x-use.
// __launch_bounds__ only sets the MIN waves/EU; amdgpu_waves_per_eu(4,4) pins
// the MAX too -> pressure target 512/4 = 128 arch VGPRs -> x lives in real
// VGPRs, loop becomes FMA-dense.

#define HW     4096      // 64*64
#define CHW    262144    // 64*4096
#define NE     2048
#define OUT_Q  4194304   // NPIX*DIM
#define WS_ET  0         // ET[j][k]: 2048*64 floats
#define WS_SE  131072    // se[j]: 2048 floats
#define WS_ACC 133120    // loss accumulator: 1 float

__global__ __launch_bounds__(256) void vq_prep(const float* __restrict__ emb,
                                               float* __restrict__ ws) {
  int bid = blockIdx.x;
  if (bid < 512) {
    // transpose: ET[j*64+k] = emb[k*2048+j]; t = k*2048+j (coalesced read)
    int t = bid * 256 + threadIdx.x;
    int k = t >> 11;
    int j = t & 2047;
    ws[WS_ET + j * 64 + k] = emb[t];
  } else {
    // se[j] = sum_k fl(e_kj^2), sequential over k
    int j = (bid - 512) * 256 + threadIdx.x;
    float s = 0.0f;
    for (int k = 0; k < 64; ++k) {
      float e = emb[k * NE + j];
      s = __fadd_rn(s, __fmul_rn(e, e));
    }
    ws[WS_SE + j] = s;
    if (j == 0) ws[WS_ACC] = 0.0f;
  }
}

#define SQ(v) __fmul_rn(v, v)
// x as 64 named scalars (x<k>_<i>, k=0..15, i=0..3)
#define XDECL(k) \
  float x##k##_0 = xp[(4*k+0)*HW], x##k##_1 = xp[(4*k+1)*HW], \
        x##k##_2 = xp[(4*k+2)*HW], x##k##_3 = xp[(4*k+3)*HW];
// opaque identity: kills rematerialization of the x loads (forces register residency)
#define XPIN(k) \
  asm volatile("" : "+v"(x##k##_0), "+v"(x##k##_1), "+v"(x##k##_2), "+v"(x##k##_3));
// two interleaved sequential-k FMA chains (independent ILP, per-chain order
// identical to rounds 1-6: k ascending, components 0,1,2,3)
#define DOTK(k) { \
  float4 ea = e0[k], eb = e1[k]; \
  d0 = __fmaf_rn(x##k##_0, ea.x, d0); d1 = __fmaf_rn(x##k##_0, eb.x, d1); \
  d0 = __fmaf_rn(x##k##_1, ea.y, d0); d1 = __fmaf_rn(x##k##_1, eb.y, d1); \
  d0 = __fmaf_rn(x##k##_2, ea.z, d0); d1 = __fmaf_rn(x##k##_2, eb.z, d1); \
  d0 = __fmaf_rn(x##k##_3, ea.w, d0); d1 = __fmaf_rn(x##k##_3, eb.w, d1); }
#define DOTALL() \
  DOTK(0) DOTK(1) DOTK(2) DOTK(3) DOTK(4) DOTK(5) DOTK(6) DOTK(7) \
  DOTK(8) DOTK(9) DOTK(10) DOTK(11) DOTK(12) DOTK(13) DOTK(14) DOTK(15)
// sx pairwise block: r0..r7 += squares of the 8 elements of (a,b) pair-chunks
#define SXB(a, b) \
  r0 = __fadd_rn(r0, SQ(a##_0)); r1 = __fadd_rn(r1, SQ(a##_1)); \
  r2 = __fadd_rn(r2, SQ(a##_2)); r3 = __fadd_rn(r3, SQ(a##_3)); \
  r4 = __fadd_rn(r4, SQ(b##_0)); r5 = __fadd_rn(r5, SQ(b##_1)); \
  r6 = __fadd_rn(r6, SQ(b##_2)); r7 = __fadd_rn(r7, SQ(b##_3));
// process the 8-code chunk currently in this wave's LDS buffer
#define CHUNK_BODY(jb_) { \
  const int jb = (jb_); \
  _Pragma("unroll") \
  for (int jl = 0; jl < 8; jl += 2) { \
    const float4* e0 = reinterpret_cast<const float4*>(&lds_e[wv][jl][0]); \
    const float4* e1 = reinterpret_cast<const float4*>(&lds_e[wv][jl + 1][0]); \
    float d0 = 0.0f, d1 = 0.0f; \
    DOTALL() \
    int j = jb + jl; \
    float dist0 = __fadd_rn(__fsub_rn(sx, __fmul_rn(2.0f, d0)), se[j]); \
    float dist1 = __fadd_rn(__fsub_rn(sx, __fmul_rn(2.0f, d1)), se[j + 1]); \
    if (dist0 < best) { best = dist0; bi = j; } \
    if (dist1 < best) { best = dist1; bi = j + 1; } \
  } }

__global__ __launch_bounds__(512)
__attribute__((amdgpu_waves_per_eu(4, 4)))
void vq_main(const float* __restrict__ inp,
             const float* __restrict__ et,
             const float* __restrict__ se,
             float* __restrict__ out,
             float* __restrict__ loss_acc) {
  __shared__ float lds_e[8][8][64];   // 16 KB: per-wave 8-code chunk buffer
  __shared__ float rv[8][64];
  __shared__ int   ri[8][64];
  __shared__ float ls[8];

  const int tid  = threadIdx.x;
  const int lane = tid & 63;
  const int wv   = tid >> 6;                    // wave id = code-slice 0..7
  const int n    = blockIdx.x * 64 + lane;      // pixel id (same set for all waves)
  const int b    = n >> 12;
  const int rem  = n & 4095;                    // block never straddles b
  const float* xp = inp + (size_t)b * CHW + rem;

  // x in 64 named scalar registers (statically indexed only)
  XDECL(0)  XDECL(1)  XDECL(2)  XDECL(3)
  XDECL(4)  XDECL(5)  XDECL(6)  XDECL(7)
  XDECL(8)  XDECL(9)  XDECL(10) XDECL(11)
  XDECL(12) XDECL(13) XDECL(14) XDECL(15)

  // sx: numpy pairwise (8 accumulators over 8-element chunks, then tree) —
  // same accumulation order as rounds 1-6
  float r0 = SQ(x0_0), r1 = SQ(x0_1), r2 = SQ(x0_2), r3 = SQ(x0_3);
  float r4 = SQ(x1_0), r5 = SQ(x1_1), r6 = SQ(x1_2), r7 = SQ(x1_3);
  SXB(x2, x3)   SXB(x4, x5)   SXB(x6, x7)   SXB(x8, x9)
  SXB(x10, x11) SXB(x12, x13) SXB(x14, x15)
  const float sx =
      __fadd_rn(__fadd_rn(__fadd_rn(r0, r1), __fadd_rn(r2, r3)),
                __fadd_rn(__fadd_rn(r4, r5), __fadd_rn(r6, r7)));

  // pin x into registers (opaque redefinition: loads above can't be remat'ed)
  XPIN(0)  XPIN(1)  XPIN(2)  XPIN(3)
  XPIN(4)  XPIN(5)  XPIN(6)  XPIN(7)
  XPIN(8)  XPIN(9)  XPIN(10) XPIN(11)
  XPIN(12) XPIN(13) XPIN(14) XPIN(15)

  // wave-private staging: slice base for this wave (256 codes = 64 KB)
  const float4* ET4 = reinterpret_cast<const float4*>(et + wv * 256 * 64);
  float4* L4 = reinterpret_cast<float4*>(&lds_e[wv][0][0]);
  const int j0 = wv * 256;

  float best = 3.402823466e38f;
  int   bi   = 0;

  // prefetch chunk 0 into registers
  float4 p0 = ET4[lane], p1 = ET4[lane + 64];

#pragma unroll 1
  for (int c = 0; c < 31; ++c) {                // chunks 0..30 (8 codes each)
    // issue next-chunk loads early (T14): latency hides under this chunk's FMAs
    const float4* src = ET4 + (c + 1) * 128;
    float4 n0 = src[lane], n1 = src[lane + 64];

    // write current chunk to wave-private LDS (DS in-order: reads below see it)
    L4[lane] = p0;
    L4[lane + 64] = p1;

    CHUNK_BODY(j0 + c * 8)
    p0 = n0; p1 = n1;
  }
  // final chunk 31 (no prefetch)
  L4[lane] = p0;
  L4[lane + 64] = p1;
  CHUNK_BODY(j0 + 31 * 8)

  rv[wv][lane] = best;
  ri[wv][lane] = bi;
  __syncthreads();

  // merge across 8 waves (slices ascending in j -> strict < keeps lowest j)
  float bv  = rv[0][lane];
  int   bix = ri[0][lane];
#pragma unroll
  for (int s = 1; s < 8; ++s) {
    float v = rv[s][lane];
    if (v < bv) { bv = v; bix = ri[s][lane]; }
  }

  // epilogue: pixel = lane, wave wv writes channels [wv*8, wv*8+8)
  const float4* qr = reinterpret_cast<const float4*>(et + (size_t)bix * 64);
  float4 qa = qr[2 * wv], qb = qr[2 * wv + 1];
  float q[8] = {qa.x, qa.y, qa.z, qa.w, qb.x, qb.y, qb.z, qb.w};
  float* op = out + (size_t)b * CHW + rem;
  float lsum = 0.0f;
#pragma unroll
  for (int i = 0; i < 8; ++i) {
    int c = wv * 8 + i;
    float xv = xp[c * HW];                 // L1-hot re-read (avoids dynamic x-reg index)
    float d  = __fsub_rn(q[i], xv);
    op[c * HW] = __fadd_rn(xv, d);         // x + (q - x)
    lsum = __fadd_rn(lsum, __fmul_rn(d, d));
  }
  if (wv == 0) out[OUT_Q + 1 + n] = (float)bix;

  // loss: wave shfl reduce -> per-wave slot -> one atomic per block
#pragma unroll
  for (int off = 32; off > 0; off >>= 1)
    lsum = __fadd_rn(lsum, __shfl_xor(lsum, off, 64));
  if (lane == 0) ls[wv] = lsum;
  __syncthreads();
  if (tid == 0) {
    float s = ls[0];
#pragma unroll
    for (int w = 1; w < 8; ++w) s = __fadd_rn(s, ls[w]);
    atomicAdd(loss_acc, s);
  }
}

__global__ void vq_final(const float* __restrict__ ws, float* __restrict__ out) {
  float m = ws[WS_ACC] / 4194304.0f;              // exact pow2 divide
  out[OUT_Q] = __fadd_rn(m, __fmul_rn(0.25f, m)); // mean + 0.25*mean
}

extern "C" void kernel_launch(void* const* d_in, const int* in_sizes, int n_in,
                              void* d_out, int out_size, void* d_ws, size_t ws_size,
                              hipStream_t stream) {
  const float* inp = (const float*)d_in[0];
  const float* emb = (const float*)d_in[1];
  float* out = (float*)d_out;
  float* ws  = (float*)d_ws;

  vq_prep<<<520, 256, 0, stream>>>(emb, ws);
  vq_main<<<1024, 512, 0, stream>>>(inp, ws + WS_ET, ws + WS_SE, out, ws + WS_ACC);
  vq_final<<<1, 1, 0, stream>>>(ws, out);
}

// Round 8
// 311.398 us; speedup vs baseline: 1.0802x; 1.0802x over previous
//
#include <hip/hip_runtime.h>

// VQ-VAE quantize: input (16,64,64,64) f32, embeddings (64,2048) f32.
// Outputs concat in d_out: quantize_st[4194304], loss[1], embed_ind[65536] (as float).
//
// Correctness-critical (absmax 0.0 rounds 1-7 — arithmetic frozen):
//   dist = fl( fl(sx - 2*dot) + se ),  dot = sequential-k FMA chain (k=0..63),
//   sx = numpy pairwise (8 accumulators + tree), se = sequential axis-0 sum,
//   argmin = first index of global minimum (exact: strict < over time-ascending
//   own-codes per thread, then merge on (v<bv)||(v==bv&&idx<bidx)).
//
// Round-8 structure: register-blocked GEMM. 256-thread block = 64 pixels x all
// codes, processed in 32 chunks of 64 codes. x-tile [k][pix] (16KB) + e-tile
// [k][cc] (16KB) in LDS (both k-major in global -> coalesced staging, no
// transpose). Thread (pg,cg) = 4 pixels x 4 codes outer-product tile: per k,
// 2x ds_read_b128 -> 16 independent FMA chains. Per-thread state ~55 regs —
// fits the allocator budget instead of fighting it (rounds 4-7: 64-VGPR
// ceiling from achievable-occupancy targeting; x-in-AGPR cost 2.55x VALU).

#define HW     4096      // 64*64
#define CHW    262144    // 64*4096
#define NE     2048
#define OUT_Q  4194304   // NPIX*DIM
#define WS_SE  0         // se[j]: 2048 floats
#define WS_ACC 2048      // loss accumulator: 1 float
#define INF    3.402823466e38f

__global__ __launch_bounds__(256) void vq_prep(const float* __restrict__ emb,
                                               float* __restrict__ ws) {
  // se[j] = sum_k fl(e_kj^2), sequential over k (numpy axis-0 reduce order)
  int j = blockIdx.x * 256 + threadIdx.x;
  float s = 0.0f;
  for (int k = 0; k < 64; ++k) {
    float e = emb[k * NE + j];
    s = __fadd_rn(s, __fmul_rn(e, e));
  }
  ws[WS_SE + j] = s;
  if (j == 0) ws[WS_ACC] = 0.0f;
}

#define SQ(v) __fmul_rn(v, v)
// update pixel i's best with acc value A at code (cj + J); strict < keeps the
// earliest code since this thread's codes are visited in ascending order.
#define UPD(i, A, J) { \
  float dist = __fadd_rn(__fsub_rn(sx##i, __fmul_rn(2.0f, A)), sej); \
  if (dist < best##i) { best##i = dist; bi##i = cj + J; } }

__global__ __launch_bounds__(256) void vq_main(const float* __restrict__ inp,
                                               const float* __restrict__ emb,
                                               const float* __restrict__ se,
                                               float* __restrict__ out,
                                               float* __restrict__ loss_acc) {
  __shared__ __align__(16) float xs[64][64];   // [k][pix]  16 KB
  __shared__ __align__(16) float es[64][64];   // [k][cc]   16 KB
  __shared__ __align__(16) float sxs[64];
  __shared__ float rvv[16][64];                // [cg][pix] merge values
  __shared__ int   rii[16][64];                // [cg][pix] merge indices
  __shared__ int   bixs[64];
  __shared__ float lss[4];

  const int tx   = threadIdx.x;
  const int b    = blockIdx.x >> 6;            // 64 blocks per batch image
  const int hw0  = (blockIdx.x & 63) * 64;     // 64-pixel contiguous run
  const int pixbase = blockIdx.x * 64;
  const float* xg = inp + (size_t)b * CHW + hw0;

  // ---- stage x-tile: xs[k][pix] = inp[b][k][hw0+pix] (coalesced, no transpose)
  {
    int pix = tx & 63, kr = tx >> 6;
#pragma unroll
    for (int pass = 0; pass < 16; ++pass) {
      int k = pass * 4 + kr;
      xs[k][pix] = xg[k * HW + pix];
    }
  }
  __syncthreads();

  // ---- sx per pixel (threads 0..63): numpy pairwise, same order as rounds 1-7
  if (tx < 64) {
    int p = tx;
    float r0 = SQ(xs[0][p]), r1 = SQ(xs[1][p]), r2 = SQ(xs[2][p]), r3 = SQ(xs[3][p]);
    float r4 = SQ(xs[4][p]), r5 = SQ(xs[5][p]), r6 = SQ(xs[6][p]), r7 = SQ(xs[7][p]);
#pragma unroll
    for (int blk = 1; blk < 8; ++blk) {
      r0 = __fadd_rn(r0, SQ(xs[blk * 8 + 0][p]));
      r1 = __fadd_rn(r1, SQ(xs[blk * 8 + 1][p]));
      r2 = __fadd_rn(r2, SQ(xs[blk * 8 + 2][p]));
      r3 = __fadd_rn(r3, SQ(xs[blk * 8 + 3][p]));
      r4 = __fadd_rn(r4, SQ(xs[blk * 8 + 4][p]));
      r5 = __fadd_rn(r5, SQ(xs[blk * 8 + 5][p]));
      r6 = __fadd_rn(r6, SQ(xs[blk * 8 + 6][p]));
      r7 = __fadd_rn(r7, SQ(xs[blk * 8 + 7][p]));
    }
    sxs[p] = __fadd_rn(__fadd_rn(__fadd_rn(r0, r1), __fadd_rn(r2, r3)),
                       __fadd_rn(__fadd_rn(r4, r5), __fadd_rn(r6, r7)));
  }
  __syncthreads();

  // ---- thread tile: pg = pixel group (4 pixels), cg = code group (4 codes/chunk)
  const int pg = tx & 15, cg = tx >> 4;
  const float4 sxv = *reinterpret_cast<const float4*>(&sxs[pg * 4]);
  const float sx0 = sxv.x, sx1 = sxv.y, sx2 = sxv.z, sx3 = sxv.w;

  float best0 = INF, best1 = INF, best2 = INF, best3 = INF;
  int   bi0 = 0, bi1 = 0, bi2 = 0, bi3 = 0;

  const float4* xr = reinterpret_cast<const float4*>(&xs[0][0]);
  const float4* er = reinterpret_cast<const float4*>(&es[0][0]);
  const int ecc = tx & 63, ekr = tx >> 6;      // e-staging coords

#pragma unroll 1
  for (int ch = 0; ch < 32; ++ch) {
    const int cbase = ch * 64;
    // prefetch this thread's se values early (global, L2-hot; consumed post-k-loop)
    const float4 sev = *reinterpret_cast<const float4*>(&se[cbase + cg * 4]);

    // stage e-chunk: es[k][cc] = emb[k][cbase+cc] (coalesced rows)
#pragma unroll
    for (int pass = 0; pass < 16; ++pass) {
      int k = pass * 4 + ekr;
      es[k][ecc] = emb[k * NE + cbase + ecc];
    }
    __syncthreads();

    // 4x4 outer-product accumulation; each acc is the reference's sequential-k chain
    float a00 = 0.f, a01 = 0.f, a02 = 0.f, a03 = 0.f;
    float a10 = 0.f, a11 = 0.f, a12 = 0.f, a13 = 0.f;
    float a20 = 0.f, a21 = 0.f, a22 = 0.f, a23 = 0.f;
    float a30 = 0.f, a31 = 0.f, a32 = 0.f, a33 = 0.f;
#pragma unroll 8
    for (int k = 0; k < 64; ++k) {
      float4 av = xr[k * 16 + pg];             // 4 pixels' x at this k
      float4 bv = er[k * 16 + cg];             // 4 codes' e at this k
      a00 = __fmaf_rn(av.x, bv.x, a00); a01 = __fmaf_rn(av.x, bv.y, a01);
      a02 = __fmaf_rn(av.x, bv.z, a02); a03 = __fmaf_rn(av.x, bv.w, a03);
      a10 = __fmaf_rn(av.y, bv.x, a10); a11 = __fmaf_rn(av.y, bv.y, a11);
      a12 = __fmaf_rn(av.y, bv.z, a12); a13 = __fmaf_rn(av.y, bv.w, a13);
      a20 = __fmaf_rn(av.z, bv.x, a20); a21 = __fmaf_rn(av.z, bv.y, a21);
      a22 = __fmaf_rn(av.z, bv.z, a22); a23 = __fmaf_rn(av.z, bv.w, a23);
      a30 = __fmaf_rn(av.w, bv.x, a30); a31 = __fmaf_rn(av.w, bv.y, a31);
      a32 = __fmaf_rn(av.w, bv.z, a32); a33 = __fmaf_rn(av.w, bv.w, a33);
    }

    // dist + per-thread argmin (codes ascending: j inner, chunk outer)
    const int cj = cbase + cg * 4;
    { const float sej = sev.x; UPD(0, a00, 0) UPD(1, a10, 0) UPD(2, a20, 0) UPD(3, a30, 0) }
    { const float sej = sev.y; UPD(0, a01, 1) UPD(1, a11, 1) UPD(2, a21, 1) UPD(3, a31, 1) }
    { const float sej = sev.z; UPD(0, a02, 2) UPD(1, a12, 2) UPD(2, a22, 2) UPD(3, a32, 2) }
    { const float sej = sev.w; UPD(0, a03, 3) UPD(1, a13, 3) UPD(2, a23, 3) UPD(3, a33, 3) }

    __syncthreads();   // protect es before next chunk's staging
  }

  // ---- merge across the 16 code-groups (sets interleave across chunks, so
  // tie-break must compare indices explicitly: lowest j among global minima)
  rvv[cg][pg * 4 + 0] = best0; rii[cg][pg * 4 + 0] = bi0;
  rvv[cg][pg * 4 + 1] = best1; rii[cg][pg * 4 + 1] = bi1;
  rvv[cg][pg * 4 + 2] = best2; rii[cg][pg * 4 + 2] = bi2;
  rvv[cg][pg * 4 + 3] = best3; rii[cg][pg * 4 + 3] = bi3;
  __syncthreads();
  if (tx < 64) {
    float bv = rvv[0][tx];
    int   bx = rii[0][tx];
#pragma unroll
    for (int g = 1; g < 16; ++g) {
      float v = rvv[g][tx];
      int   ix = rii[g][tx];
      if (v < bv || (v == bv && ix < bx)) { bv = v; bx = ix; }
    }
    bixs[tx] = bx;
    out[OUT_Q + 1 + pixbase + tx] = (float)bx;
  }
  __syncthreads();

  // ---- epilogue: quantize_st + loss. tx: pix = tx&63, channel group = tx>>6.
  {
    int pix = tx & 63, grp = tx >> 6;
    int bx = bixs[pix];
    float* op = out + (size_t)b * CHW + hw0 + pix;
    float lsum = 0.0f;
#pragma unroll
    for (int ci = 0; ci < 16; ++ci) {
      int c = grp * 16 + ci;
      float xv = xs[c][pix];                       // LDS, conflict-free
      float qv = emb[(size_t)c * NE + bx];         // gather, L2-hot
      float d  = __fsub_rn(qv, xv);
      op[c * HW] = __fadd_rn(xv, d);               // x + (q - x)
      lsum = __fadd_rn(lsum, __fmul_rn(d, d));
    }
    // loss: wave shfl reduce -> per-wave slot -> one atomic per block
#pragma unroll
    for (int off = 32; off > 0; off >>= 1)
      lsum = __fadd_rn(lsum, __shfl_xor(lsum, off, 64));
    if ((tx & 63) == 0) lss[tx >> 6] = lsum;
  }
  __syncthreads();
  if (tx == 0) {
    float s = __fadd_rn(__fadd_rn(lss[0], lss[1]), __fadd_rn(lss[2], lss[3]));
    atomicAdd(loss_acc, s);
  }
}

__global__ void vq_final(const float* __restrict__ ws, float* __restrict__ out) {
  float m = ws[WS_ACC] / 4194304.0f;              // exact pow2 divide
  out[OUT_Q] = __fadd_rn(m, __fmul_rn(0.25f, m)); // mean + 0.25*mean
}

extern "C" void kernel_launch(void* const* d_in, const int* in_sizes, int n_in,
                              void* d_out, int out_size, void* d_ws, size_t ws_size,
                              hipStream_t stream) {
  const float* inp = (const float*)d_in[0];
  const float* emb = (const float*)d_in[1];
  float* out = (float*)d_out;
  float* ws  = (float*)d_ws;

  vq_prep<<<8, 256, 0, stream>>>(emb, ws);
  vq_main<<<1024, 256, 0, stream>>>(inp, emb, ws + WS_SE, out, ws + WS_ACC);
  vq_final<<<1, 1, 0, stream>>>(ws, out);
}

// Round 9
// 302.703 us; speedup vs baseline: 1.1113x; 1.0287x over previous
//
#include <hip/hip_runtime.h>

// VQ-VAE quantize: input (16,64,64,64) f32, embeddings (64,2048) f32.
// Outputs concat in d_out: quantize_st[4194304], loss[1], embed_ind[65536] (as float).
//
// Correctness-critical (absmax 0.0 rounds 1,2,4-8 — arithmetic frozen):
//   dist = fl( fl(sx - 2*dot) + se ),  dot = sequential-k FMA chain (k=0..63),
//   sx = numpy pairwise (8 accumulators + tree), se = sequential axis-0 sum,
//   argmin = first index of global minimum (strict < per-thread over ascending
//   own-codes, then merge on (v<bv)||(v==bv&&idx<bidx)).
//
// Round-9: round-8 at 41984B LDS capped 3 blocks/CU; grid 1024 = 768+256 tail
// (measured occupancy 26.4% ≈ (37.5+12.5)/2) -> ~1.5x makespan loss. Fix:
// es double-buffered (+16KB -> 56.5KB total) = 2 blocks/CU -> 1024 blocks = 2
// perfectly balanced rounds, AND the honest LDS use sets the compiler's
// pressure target to 2 waves/SIMD (256 VGPR budget -> no AGPR shuttling).
// T14 staging: issue next-chunk loads at iter top, compute current, ds_write
// to the other buffer, ONE barrier per chunk (32 vs 64).

#define HW     4096      // 64*64
#define CHW    262144    // 64*4096
#define NE     2048
#define OUT_Q  4194304   // NPIX*DIM
#define WS_SE  0         // se[j]: 2048 floats
#define WS_ACC 2048      // loss accumulator: 1 float
#define INF    3.402823466e38f

__global__ __launch_bounds__(256) void vq_prep(const float* __restrict__ emb,
                                               float* __restrict__ ws) {
  // se[j] = sum_k fl(e_kj^2), sequential over k (numpy axis-0 reduce order)
  int j = blockIdx.x * 256 + threadIdx.x;
  float s = 0.0f;
  for (int k = 0; k < 64; ++k) {
    float e = emb[k * NE + j];
    s = __fadd_rn(s, __fmul_rn(e, e));
  }
  ws[WS_SE + j] = s;
  if (j == 0) ws[WS_ACC] = 0.0f;
}

#define SQ(v) __fmul_rn(v, v)
// update pixel i's best with acc value A at code (cj + J); strict < keeps the
// earliest code since this thread's codes are visited in ascending order.
#define UPD(i, A, J) { \
  float dist = __fadd_rn(__fsub_rn(sx##i, __fmul_rn(2.0f, A)), sej); \
  if (dist < best##i) { best##i = dist; bi##i = cj + J; } }

__global__ __launch_bounds__(256) void vq_main(const float* __restrict__ inp,
                                               const float* __restrict__ emb,
                                               const float* __restrict__ se,
                                               float* __restrict__ out,
                                               float* __restrict__ loss_acc) {
  __shared__ __align__(16) float xs[64][64];      // [k][pix]      16 KB
  __shared__ __align__(16) float es[2][64][64];   // dbuf [k][cc]  32 KB
  __shared__ __align__(16) float sxs[64];
  __shared__ float rvv[16][64];                   // [cg][pix] merge values
  __shared__ int   rii[16][64];                   // [cg][pix] merge indices
  __shared__ int   bixs[64];
  __shared__ float lss[4];

  const int tx   = threadIdx.x;
  const int b    = blockIdx.x >> 6;               // 64 blocks per batch image
  const int hw0  = (blockIdx.x & 63) * 64;        // 64-pixel contiguous run
  const int pixbase = blockIdx.x * 64;

  // staging coords: r = row-group, c = col (float4 units)
  const int r = tx >> 4, c = tx & 15;
  const float4* eg4 = reinterpret_cast<const float4*>(emb);
  const float4* xg4 = reinterpret_cast<const float4*>(inp + (size_t)b * CHW + hw0);
  float4* xs4 = reinterpret_cast<float4*>(&xs[0][0]);

  // ---- stage x-tile (vectorized): xs[k][pix], k = p*16+r, 16B cols
#pragma unroll
  for (int p = 0; p < 4; ++p)
    xs4[(p * 16 + r) * 16 + c] = xg4[(size_t)(p * 16 + r) * 1024 + c];

  // ---- prologue: issue chunk-0 e-loads into regs (T14; consumed after barrier)
  const int eb0 = r * 512 + c;                    // eg4 row r, col c
  float4 s0 = eg4[eb0];
  float4 s1 = eg4[eb0 + 8192];                    // p=1: +16 rows * 512
  float4 s2 = eg4[eb0 + 16384];
  float4 s3 = eg4[eb0 + 24576];

  __syncthreads();                                // xs ready

  // ---- sx per pixel (threads 0..63): numpy pairwise, same order rounds 1-8
  if (tx < 64) {
    int p = tx;
    float r0 = SQ(xs[0][p]), r1 = SQ(xs[1][p]), r2 = SQ(xs[2][p]), r3 = SQ(xs[3][p]);
    float r4 = SQ(xs[4][p]), r5 = SQ(xs[5][p]), r6 = SQ(xs[6][p]), r7 = SQ(xs[7][p]);
#pragma unroll
    for (int blk = 1; blk < 8; ++blk) {
      r0 = __fadd_rn(r0, SQ(xs[blk * 8 + 0][p]));
      r1 = __fadd_rn(r1, SQ(xs[blk * 8 + 1][p]));
      r2 = __fadd_rn(r2, SQ(xs[blk * 8 + 2][p]));
      r3 = __fadd_rn(r3, SQ(xs[blk * 8 + 3][p]));
      r4 = __fadd_rn(r4, SQ(xs[blk * 8 + 4][p]));
      r5 = __fadd_rn(r5, SQ(xs[blk * 8 + 5][p]));
      r6 = __fadd_rn(r6, SQ(xs[blk * 8 + 6][p]));
      r7 = __fadd_rn(r7, SQ(xs[blk * 8 + 7][p]));
    }
    sxs[p] = __fadd_rn(__fadd_rn(__fadd_rn(r0, r1), __fadd_rn(r2, r3)),
                       __fadd_rn(__fadd_rn(r4, r5), __fadd_rn(r6, r7)));
  }

  // ---- write chunk-0 e-tile into es[0] (vmcnt waits on s0..s3 here)
  {
    float4* ew = reinterpret_cast<float4*>(&es[0][0][0]);
    ew[r * 16 + c]       = s0;                    // k = p*16+r, col c
    ew[256 + r * 16 + c] = s1;
    ew[512 + r * 16 + c] = s2;
    ew[768 + r * 16 + c] = s3;
  }
  __syncthreads();                                // es[0] + sxs ready

  // ---- thread tile: pg = pixel group (4 px), cg = code group (4 codes/chunk)
  const int pg = tx & 15, cg = tx >> 4;
  const float4 sxv = *reinterpret_cast<const float4*>(&sxs[pg * 4]);
  const float sx0 = sxv.x, sx1 = sxv.y, sx2 = sxv.z, sx3 = sxv.w;

  float best0 = INF, best1 = INF, best2 = INF, best3 = INF;
  int   bi0 = 0, bi1 = 0, bi2 = 0, bi3 = 0;

  const float4* xr = reinterpret_cast<const float4*>(&xs[0][0]);

#pragma unroll 1
  for (int ch = 0; ch < 32; ++ch) {
    // issue NEXT chunk's e-loads early (uniform branch; hidden under compute)
    if (ch < 31) {
      const int nb = eb0 + (ch + 1) * 16;         // col shift: 16 float4 per chunk
      s0 = eg4[nb];
      s1 = eg4[nb + 8192];
      s2 = eg4[nb + 16384];
      s3 = eg4[nb + 24576];
    }
    // se values for this thread's 4 codes (L2-hot; consumed post-k-loop)
    const int cbase = ch * 64;
    const float4 sev = *reinterpret_cast<const float4*>(&se[cbase + cg * 4]);

    const float4* er = reinterpret_cast<const float4*>(&es[ch & 1][0][0]);

    // 4x4 outer-product; each acc is the reference's sequential-k chain
    float a00 = 0.f, a01 = 0.f, a02 = 0.f, a03 = 0.f;
    float a10 = 0.f, a11 = 0.f, a12 = 0.f, a13 = 0.f;
    float a20 = 0.f, a21 = 0.f, a22 = 0.f, a23 = 0.f;
    float a30 = 0.f, a31 = 0.f, a32 = 0.f, a33 = 0.f;
#pragma unroll 8
    for (int k = 0; k < 64; ++k) {
      float4 av = xr[k * 16 + pg];                // 4 pixels' x at this k
      float4 bv = er[k * 16 + cg];                // 4 codes' e at this k
      a00 = __fmaf_rn(av.x, bv.x, a00); a01 = __fmaf_rn(av.x, bv.y, a01);
      a02 = __fmaf_rn(av.x, bv.z, a02); a03 = __fmaf_rn(av.x, bv.w, a03);
      a10 = __fmaf_rn(av.y, bv.x, a10); a11 = __fmaf_rn(av.y, bv.y, a11);
      a12 = __fmaf_rn(av.y, bv.z, a12); a13 = __fmaf_rn(av.y, bv.w, a13);
      a20 = __fmaf_rn(av.z, bv.x, a20); a21 = __fmaf_rn(av.z, bv.y, a21);
      a22 = __fmaf_rn(av.z, bv.z, a22); a23 = __fmaf_rn(av.z, bv.w, a23);
      a30 = __fmaf_rn(av.w, bv.x, a30); a31 = __fmaf_rn(av.w, bv.y, a31);
      a32 = __fmaf_rn(av.w, bv.z, a32); a33 = __fmaf_rn(av.w, bv.w, a33);
    }

    // dist + per-thread argmin (codes ascending: j inner, chunk outer)
    const int cj = cbase + cg * 4;
    { const float sej = sev.x; UPD(0, a00, 0) UPD(1, a10, 0) UPD(2, a20, 0) UPD(3, a30, 0) }
    { const float sej = sev.y; UPD(0, a01, 1) UPD(1, a11, 1) UPD(2, a21, 1) UPD(3, a31, 1) }
    { const float sej = sev.z; UPD(0, a02, 2) UPD(1, a12, 2) UPD(2, a22, 2) UPD(3, a32, 2) }
    { const float sej = sev.w; UPD(0, a03, 3) UPD(1, a13, 3) UPD(2, a23, 3) UPD(3, a33, 3) }

    // write next chunk into the OTHER buffer (its readers are past the barrier
    // of iter ch-1; this data's readers wait at the barrier below)
    if (ch < 31) {
      float4* ew = reinterpret_cast<float4*>(&es[(ch + 1) & 1][0][0]);
      ew[r * 16 + c]       = s0;
      ew[256 + r * 16 + c] = s1;
      ew[512 + r * 16 + c] = s2;
      ew[768 + r * 16 + c] = s3;
    }
    __syncthreads();                              // one barrier per chunk
  }

  // ---- merge across the 16 code-groups (sets interleave across chunks, so
  // tie-break compares indices explicitly: lowest j among global minima)
  rvv[cg][pg * 4 + 0] = best0; rii[cg][pg * 4 + 0] = bi0;
  rvv[cg][pg * 4 + 1] = best1; rii[cg][pg * 4 + 1] = bi1;
  rvv[cg][pg * 4 + 2] = best2; rii[cg][pg * 4 + 2] = bi2;
  rvv[cg][pg * 4 + 3] = best3; rii[cg][pg * 4 + 3] = bi3;
  __syncthreads();
  if (tx < 64) {
    float bv = rvv[0][tx];
    int   bx = rii[0][tx];
#pragma unroll
    for (int g = 1; g < 16; ++g) {
      float v = rvv[g][tx];
      int   ix = rii[g][tx];
      if (v < bv || (v == bv && ix < bx)) { bv = v; bx = ix; }
    }
    bixs[tx] = bx;
    out[OUT_Q + 1 + pixbase + tx] = (float)bx;
  }
  __syncthreads();

  // ---- epilogue: quantize_st + loss. pix = tx&63, channel group = tx>>6.
  {
    int pix = tx & 63, grp = tx >> 6;
    int bx = bixs[pix];
    float* op = out + (size_t)b * CHW + hw0 + pix;
    float lsum = 0.0f;
#pragma unroll
    for (int ci = 0; ci < 16; ++ci) {
      int cch = grp * 16 + ci;
      float xv = xs[cch][pix];                    // LDS, conflict-free
      float qv = emb[(size_t)cch * NE + bx];      // gather, L2-hot
      float d  = __fsub_rn(qv, xv);
      op[cch * HW] = __fadd_rn(xv, d);            // x + (q - x)
      lsum = __fadd_rn(lsum, __fmul_rn(d, d));
    }
    // loss: wave shfl reduce -> per-wave slot -> one atomic per block
#pragma unroll
    for (int off = 32; off > 0; off >>= 1)
      lsum = __fadd_rn(lsum, __shfl_xor(lsum, off, 64));
    if ((tx & 63) == 0) lss[tx >> 6] = lsum;
  }
  __syncthreads();
  if (tx == 0) {
    float s = __fadd_rn(__fadd_rn(lss[0], lss[1]), __fadd_rn(lss[2], lss[3]));
    atomicAdd(loss_acc, s);
  }
}

__global__ void vq_final(const float* __restrict__ ws, float* __restrict__ out) {
  float m = ws[WS_ACC] / 4194304.0f;              // exact pow2 divide
  out[OUT_Q] = __fadd_rn(m, __fmul_rn(0.25f, m)); // mean + 0.25*mean
}

extern "C" void kernel_launch(void* const* d_in, const int* in_sizes, int n_in,
                              void* d_out, int out_size, void* d_ws, size_t ws_size,
                              hipStream_t stream) {
  const float* inp = (const float*)d_in[0];
  const float* emb = (const float*)d_in[1];
  float* out = (float*)d_out;
  float* ws  = (float*)d_ws;

  vq_prep<<<8, 256, 0, stream>>>(emb, ws);
  vq_main<<<1024, 256, 0, stream>>>(inp, emb, ws + WS_SE, out, ws + WS_ACC);
  vq_final<<<1, 1, 0, stream>>>(ws, out);
}

// Round 12
// 272.288 us; speedup vs baseline: 1.2354x; 1.1117x over previous
//
#include <hip/hip_runtime.h>

// VQ-VAE quantize: input (16,64,64,64) f32, embeddings (64,2048) f32.
// Outputs concat in d_out: quantize_st[4194304], loss[1], embed_ind[65536] (as float).
//
// Correctness-critical (absmax 0.0 rounds 1,2,4-9 — arithmetic frozen):
//   dist = fl( fl(sx - 2*dot) + se ),  dot = sequential-k FMA chain (k=0..63),
//   sx = numpy pairwise (8 accumulators + tree; 0-init exact), se = sequential
//   axis-0 sum, argmin = first index of global minimum (strict < per-thread
//   over time-ascending own-codes, then merge on (v<bv)||(v==bv&&idx<bidx)).
//
// Round-12 = round-10 with the macro-pasting bug fixed (digit suffix formed a
// pp-number token '0.x'; letter suffixes a/b paste cleanly). Semantics equal.
// Round 8/9 were LDS-pipe-bound (4x4 tile = 2 B/FMA; demand ~256 B/cyc/CU =
// LDS peak; VALUBusy only 66%). This round: 8px x 8codes per thread (64 FMA
// per 4 ds_read_b128 = 1 B/FMA), block = 128 px x 128-code chunks, xs+es =
// exactly 64 KB, grid 512 = one balanced round at 2 blocks/CU. Quad-interleaved
// LDS layout (q' = (q&1)*16 + q>>1) turns the 32B-stride 4-way bank conflict
// into 16B-stride 2-way (free). Merge arrays overlay dead es after the loop.

#define HW     4096      // 64*64
#define CHW    262144    // 64*4096
#define NE     2048
#define OUT_Q  4194304   // NPIX*DIM
#define WS_SE  0         // se[j]: 2048 floats
#define WS_ACC 2048      // loss accumulator: 1 float
#define INF    3.402823466e38f

__global__ __launch_bounds__(256) void vq_prep(const float* __restrict__ emb,
                                               float* __restrict__ ws) {
  // se[j] = sum_k fl(e_kj^2), sequential over k (numpy axis-0 reduce order)
  int j = blockIdx.x * 256 + threadIdx.x;
  float s = 0.0f;
  for (int k = 0; k < 64; ++k) {
    float e = emb[k * NE + j];
    s = __fadd_rn(s, __fmul_rn(e, e));
  }
  ws[WS_SE + j] = s;
  if (j == 0) ws[WS_ACC] = 0.0f;
}

// ---- float4 componentwise helpers (exact rn ops) ----
#define F4ZERO(v) { v.x = 0.f; v.y = 0.f; v.z = 0.f; v.w = 0.f; }
#define F4ADD(d, a, b) { d.x = __fadd_rn(a.x, b.x); d.y = __fadd_rn(a.y, b.y); \
                         d.z = __fadd_rn(a.z, b.z); d.w = __fadd_rn(a.w, b.w); }
#define F4SQACC(r, v) { r.x = __fadd_rn(r.x, __fmul_rn(v.x, v.x)); \
                        r.y = __fadd_rn(r.y, __fmul_rn(v.y, v.y)); \
                        r.z = __fadd_rn(r.z, __fmul_rn(v.z, v.z)); \
                        r.w = __fadd_rn(r.w, __fmul_rn(v.w, v.w)); }
// 8 FMAs into pixel p's two code-quad accumulators (k-ascending chain per acc)
#define FMA8(p, a) { \
  C##p##a_.x = __fmaf_rn(a, bv0.x, C##p##a_.x); C##p##a_.y = __fmaf_rn(a, bv0.y, C##p##a_.y); \
  C##p##a_.z = __fmaf_rn(a, bv0.z, C##p##a_.z); C##p##a_.w = __fmaf_rn(a, bv0.w, C##p##a_.w); \
  C##p##b_.x = __fmaf_rn(a, bv1.x, C##p##b_.x); C##p##b_.y = __fmaf_rn(a, bv1.y, C##p##b_.y); \
  C##p##b_.z = __fmaf_rn(a, bv1.z, C##p##b_.z); C##p##b_.w = __fmaf_rn(a, bv1.w, C##p##b_.w); }
#define DECLC(p) float4 C##p##a_, C##p##b_;
#define ZEROC(p) { F4ZERO(C##p##a_) F4ZERO(C##p##b_) }
// argmin update: pixel p, code-quad suffix q (a_/b_), component comp, code jj+J
#define UPD1(p, q, comp, J) { \
  float dd = __fadd_rn(__fsub_rn(sx_##p, __fmul_rn(2.0f, C##p##q.comp)), sej); \
  if (dd < bb##p) { bb##p = dd; ii##p = jj + (J); } }
#define UPD8(q, comp, J, SE) { const float sej = (SE); \
  UPD1(0,q,comp,J) UPD1(1,q,comp,J) UPD1(2,q,comp,J) UPD1(3,q,comp,J) \
  UPD1(4,q,comp,J) UPD1(5,q,comp,J) UPD1(6,q,comp,J) UPD1(7,q,comp,J) }

__global__ __launch_bounds__(256) void vq_main(const float* __restrict__ inp,
                                               const float* __restrict__ emb,
                                               const float* __restrict__ se,
                                               float* __restrict__ out,
                                               float* __restrict__ loss_acc) {
  __shared__ __align__(16) float xsw[8192];   // x-tile [64][128], quad-interleaved: 32 KB
  __shared__ __align__(16) float esw[8192];   // e-chunk [64][128], same layout:   32 KB
  float4* xsw4 = reinterpret_cast<float4*>(xsw);
  float4* esw4 = reinterpret_cast<float4*>(esw);
  // overlays into esw (dead after the main loop):
  float* rvv  = esw;                          // [16][128] merge values
  int*   rii  = reinterpret_cast<int*>(esw + 2048);  // [16][128] merge indices
  int*   bixs = reinterpret_cast<int*>(esw + 4096);  // [128]
  float* lss  = esw + 4224;                   // [4]

  const int tx   = threadIdx.x;
  const int b    = blockIdx.x >> 5;           // 32 blocks per batch image
  const int hw0  = (blockIdx.x & 31) << 7;    // 128-pixel contiguous run
  const int pixbase = blockIdx.x << 7;

  // staging coords: rr = row sub-index, qc = original quad, qp = interleaved pos
  const int rr = tx >> 5, qc = tx & 31;
  const int qp = ((qc & 1) << 4) | (qc >> 1);
  const float4* xg4 = reinterpret_cast<const float4*>(inp + (size_t)b * CHW);
  const float4* eg4 = reinterpret_cast<const float4*>(emb);
  const float4* se4 = reinterpret_cast<const float4*>(se);
  const int hwq = hw0 >> 2;

  // ---- prologue: stage x-tile and e-chunk-0 (reg-staged, then swizzled write)
  float4 xl0 = xg4[(0*8 + rr) * 1024 + hwq + qc];
  float4 xl1 = xg4[(1*8 + rr) * 1024 + hwq + qc];
  float4 xl2 = xg4[(2*8 + rr) * 1024 + hwq + qc];
  float4 xl3 = xg4[(3*8 + rr) * 1024 + hwq + qc];
  float4 xl4 = xg4[(4*8 + rr) * 1024 + hwq + qc];
  float4 xl5 = xg4[(5*8 + rr) * 1024 + hwq + qc];
  float4 xl6 = xg4[(6*8 + rr) * 1024 + hwq + qc];
  float4 xl7 = xg4[(7*8 + rr) * 1024 + hwq + qc];
  float4 st0 = eg4[(0*8 + rr) * 512 + qc];
  float4 st1 = eg4[(1*8 + rr) * 512 + qc];
  float4 st2 = eg4[(2*8 + rr) * 512 + qc];
  float4 st3 = eg4[(3*8 + rr) * 512 + qc];
  float4 st4 = eg4[(4*8 + rr) * 512 + qc];
  float4 st5 = eg4[(5*8 + rr) * 512 + qc];
  float4 st6 = eg4[(6*8 + rr) * 512 + qc];
  float4 st7 = eg4[(7*8 + rr) * 512 + qc];
  xsw4[(0*8 + rr) * 32 + qp] = xl0;  xsw4[(1*8 + rr) * 32 + qp] = xl1;
  xsw4[(2*8 + rr) * 32 + qp] = xl2;  xsw4[(3*8 + rr) * 32 + qp] = xl3;
  xsw4[(4*8 + rr) * 32 + qp] = xl4;  xsw4[(5*8 + rr) * 32 + qp] = xl5;
  xsw4[(6*8 + rr) * 32 + qp] = xl6;  xsw4[(7*8 + rr) * 32 + qp] = xl7;
  esw4[(0*8 + rr) * 32 + qp] = st0;  esw4[(1*8 + rr) * 32 + qp] = st1;
  esw4[(2*8 + rr) * 32 + qp] = st2;  esw4[(3*8 + rr) * 32 + qp] = st3;
  esw4[(4*8 + rr) * 32 + qp] = st4;  esw4[(5*8 + rr) * 32 + qp] = st5;
  esw4[(6*8 + rr) * 32 + qp] = st6;  esw4[(7*8 + rr) * 32 + qp] = st7;
  __syncthreads();                            // xs + es(ch0) ready

  // ---- thread tile: pg -> pixels 8pg..8pg+7, cg -> codes 8cg..8cg+7 per chunk
  const int pg = tx & 15, cg = tx >> 4;

  // sx for this thread's 8 pixels: numpy pairwise (8 accs over k%8, tree), two
  // 4-pixel passes. Zero-init + fadd(fmul) is exact (0+x == x).
  float sx_0, sx_1, sx_2, sx_3, sx_4, sx_5, sx_6, sx_7;
  {
    float4 r0, r1, r2, r3, r4, r5, r6, r7;
    F4ZERO(r0) F4ZERO(r1) F4ZERO(r2) F4ZERO(r3)
    F4ZERO(r4) F4ZERO(r5) F4ZERO(r6) F4ZERO(r7)
#pragma unroll
    for (int blk = 0; blk < 8; ++blk) {
      float4 v;
      v = xsw4[(blk*8 + 0) * 32 + pg]; F4SQACC(r0, v)
      v = xsw4[(blk*8 + 1) * 32 + pg]; F4SQACC(r1, v)
      v = xsw4[(blk*8 + 2) * 32 + pg]; F4SQACC(r2, v)
      v = xsw4[(blk*8 + 3) * 32 + pg]; F4SQACC(r3, v)
      v = xsw4[(blk*8 + 4) * 32 + pg]; F4SQACC(r4, v)
      v = xsw4[(blk*8 + 5) * 32 + pg]; F4SQACC(r5, v)
      v = xsw4[(blk*8 + 6) * 32 + pg]; F4SQACC(r6, v)
      v = xsw4[(blk*8 + 7) * 32 + pg]; F4SQACC(r7, v)
    }
    float4 t01, t23, t45, t67, ta, tb, sq;
    F4ADD(t01, r0, r1) F4ADD(t23, r2, r3) F4ADD(t45, r4, r5) F4ADD(t67, r6, r7)
    F4ADD(ta, t01, t23) F4ADD(tb, t45, t67) F4ADD(sq, ta, tb)
    sx_0 = sq.x; sx_1 = sq.y; sx_2 = sq.z; sx_3 = sq.w;
  }
  {
    float4 r0, r1, r2, r3, r4, r5, r6, r7;
    F4ZERO(r0) F4ZERO(r1) F4ZERO(r2) F4ZERO(r3)
    F4ZERO(r4) F4ZERO(r5) F4ZERO(r6) F4ZERO(r7)
#pragma unroll
    for (int blk = 0; blk < 8; ++blk) {
      float4 v;
      v = xsw4[(blk*8 + 0) * 32 + 16 + pg]; F4SQACC(r0, v)
      v = xsw4[(blk*8 + 1) * 32 + 16 + pg]; F4SQACC(r1, v)
      v = xsw4[(blk*8 + 2) * 32 + 16 + pg]; F4SQACC(r2, v)
      v = xsw4[(blk*8 + 3) * 32 + 16 + pg]; F4SQACC(r3, v)
      v = xsw4[(blk*8 + 4) * 32 + 16 + pg]; F4SQACC(r4, v)
      v = xsw4[(blk*8 + 5) * 32 + 16 + pg]; F4SQACC(r5, v)
      v = xsw4[(blk*8 + 6) * 32 + 16 + pg]; F4SQACC(r6, v)
      v = xsw4[(blk*8 + 7) * 32 + 16 + pg]; F4SQACC(r7, v)
    }
    float4 t01, t23, t45, t67, ta, tb, sq;
    F4ADD(t01, r0, r1) F4ADD(t23, r2, r3) F4ADD(t45, r4, r5) F4ADD(t67, r6, r7)
    F4ADD(ta, t01, t23) F4ADD(tb, t45, t67) F4ADD(sq, ta, tb)
    sx_4 = sq.x; sx_5 = sq.y; sx_6 = sq.z; sx_7 = sq.w;
  }

  float bb0 = INF, bb1 = INF, bb2 = INF, bb3 = INF;
  float bb4 = INF, bb5 = INF, bb6 = INF, bb7 = INF;
  int   ii0 = 0, ii1 = 0, ii2 = 0, ii3 = 0, ii4 = 0, ii5 = 0, ii6 = 0, ii7 = 0;

#pragma unroll 1
  for (int ch = 0; ch < 16; ++ch) {
    // T14: issue next chunk's e-loads at chunk top (hidden under 64-k compute)
    if (ch < 15) {
      const int cb = (ch + 1) * 32;
      st0 = eg4[(0*8 + rr) * 512 + cb + qc];
      st1 = eg4[(1*8 + rr) * 512 + cb + qc];
      st2 = eg4[(2*8 + rr) * 512 + cb + qc];
      st3 = eg4[(3*8 + rr) * 512 + cb + qc];
      st4 = eg4[(4*8 + rr) * 512 + cb + qc];
      st5 = eg4[(5*8 + rr) * 512 + cb + qc];
      st6 = eg4[(6*8 + rr) * 512 + cb + qc];
      st7 = eg4[(7*8 + rr) * 512 + cb + qc];
    }
    const float4 sea = se4[ch * 32 + cg * 2];      // this thread's codes, se
    const float4 seb = se4[ch * 32 + cg * 2 + 1];

    DECLC(0) DECLC(1) DECLC(2) DECLC(3) DECLC(4) DECLC(5) DECLC(6) DECLC(7)
    ZEROC(0) ZEROC(1) ZEROC(2) ZEROC(3) ZEROC(4) ZEROC(5) ZEROC(6) ZEROC(7)

#pragma unroll 8
    for (int k = 0; k < 64; ++k) {
      const float4 av0 = xsw4[k * 32 + pg];        // pixels 8pg..8pg+3
      const float4 av1 = xsw4[k * 32 + 16 + pg];   // pixels 8pg+4..8pg+7
      const float4 bv0 = esw4[k * 32 + cg];        // codes 8cg..8cg+3
      const float4 bv1 = esw4[k * 32 + 16 + cg];   // codes 8cg+4..8cg+7
      FMA8(0, av0.x) FMA8(1, av0.y) FMA8(2, av0.z) FMA8(3, av0.w)
      FMA8(4, av1.x) FMA8(5, av1.y) FMA8(6, av1.z) FMA8(7, av1.w)
    }

    // dist + per-thread argmin (ascending j: quad a comps, then quad b comps)
    const int jj = ch * 128 + cg * 8;
    UPD8(a_, x, 0, sea.x) UPD8(a_, y, 1, sea.y) UPD8(a_, z, 2, sea.z) UPD8(a_, w, 3, sea.w)
    UPD8(b_, x, 4, seb.x) UPD8(b_, y, 5, seb.y) UPD8(b_, z, 6, seb.z) UPD8(b_, w, 7, seb.w)

    __syncthreads();                               // all readers done with es
    if (ch < 15) {
      esw4[(0*8 + rr) * 32 + qp] = st0;  esw4[(1*8 + rr) * 32 + qp] = st1;
      esw4[(2*8 + rr) * 32 + qp] = st2;  esw4[(3*8 + rr) * 32 + qp] = st3;
      esw4[(4*8 + rr) * 32 + qp] = st4;  esw4[(5*8 + rr) * 32 + qp] = st5;
      esw4[(6*8 + rr) * 32 + qp] = st6;  esw4[(7*8 + rr) * 32 + qp] = st7;
    }
    __syncthreads();                               // es ready (or loop exit)
  }

  // ---- merge across the 16 code-groups (overlay arrays in dead es region)
  rvv[cg * 128 + pg * 8 + 0] = bb0;  rii[cg * 128 + pg * 8 + 0] = ii0;
  rvv[cg * 128 + pg * 8 + 1] = bb1;  rii[cg * 128 + pg * 8 + 1] = ii1;
  rvv[cg * 128 + pg * 8 + 2] = bb2;  rii[cg * 128 + pg * 8 + 2] = ii2;
  rvv[cg * 128 + pg * 8 + 3] = bb3;  rii[cg * 128 + pg * 8 + 3] = ii3;
  rvv[cg * 128 + pg * 8 + 4] = bb4;  rii[cg * 128 + pg * 8 + 4] = ii4;
  rvv[cg * 128 + pg * 8 + 5] = bb5;  rii[cg * 128 + pg * 8 + 5] = ii5;
  rvv[cg * 128 + pg * 8 + 6] = bb6;  rii[cg * 128 + pg * 8 + 6] = ii6;
  rvv[cg * 128 + pg * 8 + 7] = bb7;  rii[cg * 128 + pg * 8 + 7] = ii7;
  __syncthreads();
  if (tx < 128) {
    float bv = rvv[tx];
    int   bx = rii[tx];
#pragma unroll
    for (int g = 1; g < 16; ++g) {
      float v  = rvv[g * 128 + tx];
      int   ix = rii[g * 128 + tx];
      if (v < bv || (v == bv && ix < bx)) { bv = v; bx = ix; }  // lowest j wins
    }
    bixs[tx] = bx;
    out[OUT_Q + 1 + pixbase + tx] = (float)bx;
  }
  __syncthreads();

  // ---- epilogue: quantize_st + loss. pix = tx&127, channel half = tx>>7.
  {
    const int pix = tx & 127, half = tx >> 7;
    const int qx = pix >> 2, cmp = pix & 3;
    const int qpix = (((qx & 1) << 4) | (qx >> 1)) * 4 + cmp;  // swizzled col
    const int bx = bixs[pix];
    float* op = out + (size_t)b * CHW + hw0 + pix;
    float lsum = 0.0f;
#pragma unroll
    for (int ci = 0; ci < 32; ++ci) {
      const int c = half * 32 + ci;
      float xv = xsw[c * 128 + qpix];              // LDS (2-way max)
      float qv = emb[(size_t)c * NE + bx];         // gather, L2-hot
      float d  = __fsub_rn(qv, xv);
      op[c * HW] = __fadd_rn(xv, d);               // x + (q - x)
      lsum = __fadd_rn(lsum, __fmul_rn(d, d));
    }
#pragma unroll
    for (int off = 32; off > 0; off >>= 1)
      lsum = __fadd_rn(lsum, __shfl_xor(lsum, off, 64));
    if ((tx & 63) == 0) lss[tx >> 6] = lsum;
  }
  __syncthreads();
  if (tx == 0) {
    float s = __fadd_rn(__fadd_rn(lss[0], lss[1]), __fadd_rn(lss[2], lss[3]));
    atomicAdd(loss_acc, s);
  }
}

__global__ void vq_final(const float* __restrict__ ws, float* __restrict__ out) {
  float m = ws[WS_ACC] / 4194304.0f;              // exact pow2 divide
  out[OUT_Q] = __fadd_rn(m, __fmul_rn(0.25f, m)); // mean + 0.25*mean
}

extern "C" void kernel_launch(void* const* d_in, const int* in_sizes, int n_in,
                              void* d_out, int out_size, void* d_ws, size_t ws_size,
                              hipStream_t stream) {
  const float* inp = (const float*)d_in[0];
  const float* emb = (const float*)d_in[1];
  float* out = (float*)d_out;
  float* ws  = (float*)d_ws;

  vq_prep<<<8, 256, 0, stream>>>(emb, ws);
  vq_main<<<512, 256, 0, stream>>>(inp, emb, ws + WS_SE, out, ws + WS_ACC);
  vq_final<<<1, 1, 0, stream>>>(ws, out);
}